// Round 1
// baseline (1536.576 us; speedup 1.0000x reference)
//
#include <hip/hip_runtime.h>
#include <math.h>

#define HH 128
#define WW 128
#define BB 4
#define HW (HH*WW)

// ---------------------------------------------------------------------------
// 3x3 conv, stride 1, pad 1, NCHW, f32. Direct conv with LDS input tile.
// Block = 256 threads = 16x16 output pixels. Each block computes OCPB output
// channels for its tile. CONCAT=true: input = cat([inA(64), inB(64), inC(2)]).
// ---------------------------------------------------------------------------
template<int CIN, int OCPB, bool RELU, bool CONCAT>
__global__ __launch_bounds__(256) void conv3x3_k(
    const float* __restrict__ inA, const float* __restrict__ inB,
    const float* __restrict__ inC,
    const float* __restrict__ wgt, const float* __restrict__ bias,
    float* __restrict__ out, int OCtot)
{
    __shared__ float tile[18 * 18];

    const int tileId = blockIdx.x;          // 64 tiles (8x8)
    const int h0 = (tileId >> 3) << 4;
    const int w0 = (tileId & 7) << 4;
    const int oc0 = blockIdx.y * OCPB;
    const int b = blockIdx.z;
    const int t = threadIdx.x;
    const int px = t & 15, py = t >> 4;
    const int oh = h0 + py, ow = w0 + px;

    float acc[OCPB];
#pragma unroll
    for (int o = 0; o < OCPB; ++o) acc[o] = bias[oc0 + o];

    for (int c = 0; c < CIN; ++c) {
        const float* plane;
        if (CONCAT) {
            if (c < 64)       plane = inA + ((size_t)b * 64 + c) * HW;
            else if (c < 128) plane = inB + ((size_t)b * 64 + (c - 64)) * HW;
            else              plane = inC + ((size_t)b * 2 + (c - 128)) * HW;
        } else {
            plane = inA + ((size_t)b * CIN + c) * HW;
        }

        __syncthreads();
        for (int i = t; i < 18 * 18; i += 256) {
            const int ty = i / 18, tx = i % 18;
            const int gy = h0 - 1 + ty, gx = w0 - 1 + tx;
            float v = 0.f;
            if (gy >= 0 && gy < HH && gx >= 0 && gx < WW) v = plane[gy * WW + gx];
            tile[i] = v;
        }
        __syncthreads();

        float v[9];
#pragma unroll
        for (int ky = 0; ky < 3; ++ky)
#pragma unroll
            for (int kx = 0; kx < 3; ++kx)
                v[ky * 3 + kx] = tile[(py + ky) * 18 + (px + kx)];

        const float* wp = wgt + ((size_t)oc0 * CIN + c) * 9;
#pragma unroll
        for (int o = 0; o < OCPB; ++o) {
            const float* w9 = wp + (size_t)o * CIN * 9;
#pragma unroll
            for (int k = 0; k < 9; ++k)
                acc[o] = fmaf(w9[k], v[k], acc[o]);
        }
    }

#pragma unroll
    for (int o = 0; o < OCPB; ++o) {
        float r = acc[o];
        if (RELU) r = (r >= 0.f) ? r : 0.1f * r;
        out[(((size_t)b * OCtot + oc0 + o) * HH + oh) * WW + ow] = r;
    }
}

// ---------------------------------------------------------------------------
// Transpose deform weight [O=64][C=64][9] -> [(g*9+k)*8+c][O=64]
// so the deform inner loop over O reads 64 contiguous floats (scalar-cached).
// ---------------------------------------------------------------------------
__global__ void transpose_w_k(const float* __restrict__ wsrc, float* __restrict__ wdst)
{
    int i = blockIdx.x * 256 + threadIdx.x;   // over 64*64*9 = 36864
    if (i >= 64 * 64 * 9) return;
    int o  = i / 576;
    int r  = i % 576;
    int ch = r / 9;
    int k  = r % 9;
    int g = ch >> 3, c = ch & 7;
    wdst[(((g * 9 + k) * 8) + c) * 64 + o] = wsrc[i];
}

// ---------------------------------------------------------------------------
// Deformable conv: one thread per output pixel (b,h,w); acc over all 64
// output channels in registers. Offsets/mask computed inline from o4 + flow.
// ---------------------------------------------------------------------------
__global__ __launch_bounds__(256) void deform_k(
    const float* __restrict__ x, const float* __restrict__ o4,
    const float* __restrict__ flow, const float* __restrict__ wt,
    const float* __restrict__ bias, float* __restrict__ out)
{
    const int tid = blockIdx.x * 256 + threadIdx.x;   // 0 .. B*H*W-1
    const int w = tid & (WW - 1);
    const int h = (tid >> 7) & (HH - 1);
    const int b = tid >> 14;

    float acc[64];
#pragma unroll
    for (int o = 0; o < 64; ++o) acc[o] = 0.f;

    const size_t pix = (size_t)h * WW + w;
    const float* o4b = o4 + (size_t)b * 216 * HW + pix;
    const float fy = flow[((size_t)b * 2 + 1) * HW + pix];
    const float fx = flow[((size_t)b * 2 + 0) * HW + pix];
    const float* xb = x + (size_t)b * 64 * HW;

    for (int g = 0; g < 8; ++g) {
        const float* xg = xb + (size_t)(g * 8) * HW;
#pragma unroll
        for (int k = 0; k < 9; ++k) {
            const int coff = g * 18 + k * 2;
            const float oy = o4b[(size_t)coff * HW];
            const float ox = o4b[(size_t)(coff + 1) * HW];
            float m = o4b[(size_t)(144 + g * 9 + k) * HW];
            m = 1.f / (1.f + expf(-m));

            const float py = 10.f * tanhf(oy) + fy + (float)h + (float)(k / 3 - 1);
            const float px = 10.f * tanhf(ox) + fx + (float)w + (float)(k % 3 - 1);

            const float y0f = floorf(py), x0f = floorf(px);
            const float ly = py - y0f, lx = px - x0f;
            const int iy0 = (int)y0f, ix0 = (int)x0f;
            const int iy1 = iy0 + 1,  ix1 = ix0 + 1;

            const float vy0 = (iy0 >= 0 && iy0 < HH) ? 1.f : 0.f;
            const float vy1 = (iy1 >= 0 && iy1 < HH) ? 1.f : 0.f;
            const float vx0 = (ix0 >= 0 && ix0 < WW) ? 1.f : 0.f;
            const float vx1 = (ix1 >= 0 && ix1 < WW) ? 1.f : 0.f;

            const int cy0 = min(max(iy0, 0), HH - 1);
            const int cy1 = min(max(iy1, 0), HH - 1);
            const int cx0 = min(max(ix0, 0), WW - 1);
            const int cx1 = min(max(ix1, 0), WW - 1);

            const float w00 = (1.f - ly) * (1.f - lx) * vy0 * vx0 * m;
            const float w01 = (1.f - ly) * lx         * vy0 * vx1 * m;
            const float w10 = ly         * (1.f - lx) * vy1 * vx0 * m;
            const float w11 = ly         * lx         * vy1 * vx1 * m;

            const int i00 = cy0 * WW + cx0, i01 = cy0 * WW + cx1;
            const int i10 = cy1 * WW + cx0, i11 = cy1 * WW + cx1;

            float s[8];
#pragma unroll
            for (int c = 0; c < 8; ++c) {
                const float* pl = xg + (size_t)c * HW;
                s[c] = w00 * pl[i00] + w01 * pl[i01] + w10 * pl[i10] + w11 * pl[i11];
            }

            const float* wrow = wt + (size_t)((g * 9 + k) * 8) * 64;
#pragma unroll
            for (int c = 0; c < 8; ++c) {
#pragma unroll
                for (int o = 0; o < 64; ++o)
                    acc[o] = fmaf(wrow[c * 64 + o], s[c], acc[o]);
            }
        }
    }

#pragma unroll
    for (int o = 0; o < 64; ++o)
        out[((size_t)b * 64 + o) * HW + pix] = acc[o] + bias[o];
}

// ---------------------------------------------------------------------------
extern "C" void kernel_launch(void* const* d_in, const int* in_sizes, int n_in,
                              void* d_out, int out_size, void* d_ws, size_t ws_size,
                              hipStream_t stream)
{
    const float* x     = (const float*)d_in[0];
    const float* xw    = (const float*)d_in[1];
    const float* xc    = (const float*)d_in[2];
    const float* flow  = (const float*)d_in[3];
    const float* w1    = (const float*)d_in[4];
    const float* b1    = (const float*)d_in[5];
    const float* w2    = (const float*)d_in[6];
    const float* b2    = (const float*)d_in[7];
    const float* w3    = (const float*)d_in[8];
    const float* b3    = (const float*)d_in[9];
    const float* w4    = (const float*)d_in[10];
    const float* b4    = (const float*)d_in[11];
    const float* wt    = (const float*)d_in[12];
    const float* bias  = (const float*)d_in[13];
    float* out = (float*)d_out;

    char* ws = (char*)d_ws;
    // ws layout:
    //   slot0 : o1, later o3        16,777,216 B
    //   slot1 : o2                  16,777,216 B
    //   slot2 : o4                  56,623,104 B
    //   slot3 : transposed weight      147,456 B   (total ~90.3 MB)
    float* o1  = (float*)(ws);
    float* o2  = (float*)(ws + 16777216);
    float* o4  = (float*)(ws + 2 * 16777216);
    float* wtr = (float*)(ws + 2 * 16777216 + 56623104);

    const dim3 blk(256);

    // conv1: 130 -> 64, lrelu (concat input)
    conv3x3_k<130, 16, true, true><<<dim3(64, 4, BB), blk, 0, stream>>>(
        xw, xc, flow, w1, b1, o1, 64);
    // conv2: 64 -> 64, lrelu
    conv3x3_k<64, 16, true, false><<<dim3(64, 4, BB), blk, 0, stream>>>(
        o1, nullptr, nullptr, w2, b2, o2, 64);
    // conv3: 64 -> 64, lrelu   (write into slot0)
    conv3x3_k<64, 16, true, false><<<dim3(64, 4, BB), blk, 0, stream>>>(
        o2, nullptr, nullptr, w3, b3, o1, 64);
    // conv4: 64 -> 216, no act
    conv3x3_k<64, 24, false, false><<<dim3(64, 9, BB), blk, 0, stream>>>(
        o1, nullptr, nullptr, w4, b4, o4, 216);

    transpose_w_k<<<dim3((36864 + 255) / 256), blk, 0, stream>>>(wt, wtr);

    deform_k<<<dim3((BB * HW) / 256), blk, 0, stream>>>(
        x, o4, flow, wtr, bias, out);
}